// Round 2
// baseline (1026.074 us; speedup 1.0000x reference)
//
#include <hip/hip_runtime.h>

#define LEAKY(v) ((v) > 0.0f ? (v) : 0.1f * (v))

// Zero the accumulator region of ws (float4-aligned) and the 10-float output.
__global__ void k_zero(float4* p, size_t n4, float* out) {
    size_t i = (size_t)blockIdx.x * blockDim.x + threadIdx.x;
    size_t stride = (size_t)gridDim.x * blockDim.x;
    float4 z = {0.f, 0.f, 0.f, 0.f};
    for (; i < n4; i += stride) p[i] = z;
    if (blockIdx.x == 0 && threadIdx.x < 10) out[threadIdx.x] = 0.f;
}

// deg[dst] += 1 per edge (self-loop added later as +1).
__global__ void k_deg(const int* __restrict__ dst, int E, int* __restrict__ deg) {
    int e = blockIdx.x * blockDim.x + threadIdx.x;
    if (e < E) atomicAdd(&deg[dst[e]], 1);
}

__global__ void k_dinv(const int* __restrict__ deg, float* __restrict__ dinv, int N) {
    int i = blockIdx.x * blockDim.x + threadIdx.x;
    if (i < N) dinv[i] = rsqrtf((float)deg[i] + 1.0f);
}

// Layer-1 aggregation is scalar: acc1[dst] += x[src]*dinv[src]
__global__ void k_scatter1(const int* __restrict__ src, const int* __restrict__ dst,
                           const float* __restrict__ x, const float* __restrict__ dinv,
                           float* __restrict__ acc1, int E) {
    int e = blockIdx.x * blockDim.x + threadIdx.x;
    if (e < E) {
        int s = src[e];
        atomicAdd(&acc1[dst[e]], x[s] * dinv[s]);
    }
}

// Per (node, channel c<32): s1 = dinv*(acc1 + dinv*x); h1[j] = leaky(s1*W1[j]+b1[j]);
// t2s[i][c] = dinv * sum_j h1[j]*W2[j][c]
__global__ void k_layer1(const float* __restrict__ x, const float* __restrict__ dinv,
                         const float* __restrict__ acc1, const float* __restrict__ W1,
                         const float* __restrict__ b1, const float* __restrict__ W2,
                         float* __restrict__ t2s, int N) {
    __shared__ float sW1[64], sb1[64], sW2[64 * 32];
    for (int t = threadIdx.x; t < 64 * 32; t += blockDim.x) sW2[t] = W2[t];
    for (int t = threadIdx.x; t < 64; t += blockDim.x) { sW1[t] = W1[t]; sb1[t] = b1[t]; }
    __syncthreads();
    int tid = blockIdx.x * blockDim.x + threadIdx.x;
    int i = tid >> 5, c = tid & 31;
    if (i >= N) return;
    float di = dinv[i];
    float s1 = di * (acc1[i] + di * x[i]);
    float acc = 0.f;
#pragma unroll
    for (int j = 0; j < 64; j++) {
        float h = s1 * sW1[j] + sb1[j];
        h = LEAKY(h);
        acc += h * sW2[j * 32 + c];
    }
    t2s[(size_t)i * 32 + c] = di * acc;
}

// Per (edge, channel): acc2[dst][c] += t2s[src][c]
__global__ void k_scatter2(const int* __restrict__ src, const int* __restrict__ dst,
                           const float* __restrict__ t2s, float* __restrict__ acc2, int E) {
    int tid = blockIdx.x * blockDim.x + threadIdx.x;
    int e = tid >> 5, c = tid & 31;
    if (e < E) atomicAdd(&acc2[(size_t)dst[e] * 32 + c], t2s[(size_t)src[e] * 32 + c]);
}

// Per (node, k<10 padded to 16): h2[c] = leaky(dinv*(acc2+t2s)+b2);
// t3s[i][k] = dinv * sum_c h2[c]*W3[c][k]
__global__ void k_layer2(const float* __restrict__ dinv, const float* __restrict__ acc2,
                         const float* __restrict__ t2s, const float* __restrict__ b2,
                         const float* __restrict__ W3, float* __restrict__ t3s, int N) {
    __shared__ float sb2[32], sW3[32 * 10];
    for (int t = threadIdx.x; t < 32 * 10; t += blockDim.x) sW3[t] = W3[t];  // FIX: was `if (tid<320)` with 256 threads
    for (int t = threadIdx.x; t < 32; t += blockDim.x) sb2[t] = b2[t];
    __syncthreads();
    int tid = blockIdx.x * blockDim.x + threadIdx.x;
    int i = tid >> 4, k = tid & 15;
    if (i >= N || k >= 10) return;
    float di = dinv[i];
    float acc = 0.f;
#pragma unroll
    for (int c = 0; c < 32; c++) {
        float h = di * (acc2[(size_t)i * 32 + c] + t2s[(size_t)i * 32 + c]) + sb2[c];
        h = LEAKY(h);
        acc += h * sW3[c * 10 + k];
    }
    t3s[(size_t)i * 10 + k] = di * acc;
}

// Per (edge, k<10 padded to 16): acc3[dst][k] += t3s[src][k]
__global__ void k_scatter3(const int* __restrict__ src, const int* __restrict__ dst,
                           const float* __restrict__ t3s, float* __restrict__ acc3, int E) {
    int tid = blockIdx.x * blockDim.x + threadIdx.x;
    int e = tid >> 4, k = tid & 15;
    if (e < E && k < 10) atomicAdd(&acc3[(size_t)dst[e] * 10 + k], t3s[(size_t)src[e] * 10 + k]);
}

// h3[i][k] = dinv*(acc3+t3s)+b3[k]; out[k] = mean_i h3[i][k]
__global__ void k_final(const float* __restrict__ dinv, const float* __restrict__ acc3,
                        const float* __restrict__ t3s, const float* __restrict__ b3,
                        float* __restrict__ out, int N, float invN) {
    __shared__ float sred[10];
    if (threadIdx.x < 10) sred[threadIdx.x] = 0.f;
    __syncthreads();
    int i = blockIdx.x * blockDim.x + threadIdx.x;
    if (i < N) {
        float di = dinv[i];
#pragma unroll
        for (int k = 0; k < 10; k++) {
            float v = di * (acc3[(size_t)i * 10 + k] + t3s[(size_t)i * 10 + k]) + b3[k];
            atomicAdd(&sred[k], v * invN);
        }
    }
    __syncthreads();
    if (threadIdx.x < 10) atomicAdd(&out[threadIdx.x], sred[threadIdx.x]);
}

extern "C" void kernel_launch(void* const* d_in, const int* in_sizes, int n_in,
                              void* d_out, int out_size, void* d_ws, size_t ws_size,
                              hipStream_t stream) {
    const float* x   = (const float*)d_in[0];
    const int*   ei  = (const int*)d_in[1];
    const float* W1  = (const float*)d_in[2];
    const float* b1  = (const float*)d_in[3];
    const float* W2  = (const float*)d_in[4];
    const float* b2  = (const float*)d_in[5];
    const float* W3  = (const float*)d_in[6];
    const float* b3  = (const float*)d_in[7];
    float* out = (float*)d_out;

    const int N = in_sizes[0];        // x is [N,1]
    const int E = in_sizes[1] / 2;    // edge_index is [2,E]
    const int* src = ei;
    const int* dst = ei + E;

    auto align256 = [](size_t v) { return (v + 255) & ~(size_t)255; };
    char* ws = (char*)d_ws;
    size_t off = 0;
    // ---- zeroed region (accumulators) ----
    size_t o_deg  = off; off = align256(off + (size_t)N * 4);
    size_t o_acc1 = off; off = align256(off + (size_t)N * 4);
    size_t o_acc2 = off; off = align256(off + (size_t)N * 32 * 4);
    size_t o_acc3 = off; off = align256(off + (size_t)N * 10 * 4);
    size_t zero_bytes = off;          // multiple of 256 -> /16 ok
    // ---- write-before-read region ----
    size_t o_dinv = off; off = align256(off + (size_t)N * 4);
    size_t o_t2s  = off; off = align256(off + (size_t)N * 32 * 4);
    size_t o_t3s  = off; off = align256(off + (size_t)N * 10 * 4);

    int*   deg  = (int*)(ws + o_deg);
    float* acc1 = (float*)(ws + o_acc1);
    float* acc2 = (float*)(ws + o_acc2);
    float* acc3 = (float*)(ws + o_acc3);
    float* dinv = (float*)(ws + o_dinv);
    float* t2s  = (float*)(ws + o_t2s);
    float* t3s  = (float*)(ws + o_t3s);

    const int B = 256;
    // zero accumulators + out
    k_zero<<<2048, B, 0, stream>>>((float4*)ws, zero_bytes / 16, out);
    // degree
    k_deg<<<(E + B - 1) / B, B, 0, stream>>>(dst, E, deg);
    // dinv
    k_dinv<<<(N + B - 1) / B, B, 0, stream>>>(deg, dinv, N);
    // layer 1 scalar scatter
    k_scatter1<<<(E + B - 1) / B, B, 0, stream>>>(src, dst, x, dinv, acc1, E);
    // layer 1 dense -> t2s (pre-scaled by dinv)
    k_layer1<<<((size_t)N * 32 + B - 1) / B, B, 0, stream>>>(x, dinv, acc1, W1, b1, W2, t2s, N);
    // layer 2 scatter (32 channels/edge)
    k_scatter2<<<((size_t)E * 32 + B - 1) / B, B, 0, stream>>>(src, dst, t2s, acc2, E);
    // layer 2 dense -> t3s
    k_layer2<<<((size_t)N * 16 + B - 1) / B, B, 0, stream>>>(dinv, acc2, t2s, b2, W3, t3s, N);
    // layer 3 scatter (10 channels/edge, padded to 16)
    k_scatter3<<<((size_t)E * 16 + B - 1) / B, B, 0, stream>>>(src, dst, t3s, acc3, E);
    // epilogue + mean
    k_final<<<(N + B - 1) / B, B, 0, stream>>>(dinv, acc3, t3s, b3, out, N, 1.0f / (float)N);
}

// Round 3
// 822.853 us; speedup vs baseline: 1.2470x; 1.2470x over previous
//
#include <hip/hip_runtime.h>

#define LEAKY(v) ((v) > 0.0f ? (v) : 0.1f * (v))

__device__ __forceinline__ int wave_iscan(int v, int lane) {
#pragma unroll
    for (int off = 1; off < 64; off <<= 1) {
        int n = __shfl_up(v, off, 64);
        if (lane >= off) v += n;
    }
    return v;
}

// Zero deg region (float4-aligned bytes) and out[10].
__global__ void k_zero(float4* p, size_t n4, float* out) {
    size_t i = (size_t)blockIdx.x * blockDim.x + threadIdx.x;
    size_t stride = (size_t)gridDim.x * blockDim.x;
    float4 z = {0.f, 0.f, 0.f, 0.f};
    for (; i < n4; i += stride) p[i] = z;
    if (blockIdx.x == 0 && threadIdx.x < 10) out[threadIdx.x] = 0.f;
}

__global__ void k_deg(const int* __restrict__ dst, int E, int* __restrict__ deg) {
    int e = blockIdx.x * blockDim.x + threadIdx.x;
    if (e < E) atomicAdd(&deg[dst[e]], 1);
}

// ---- exclusive scan of deg (1024 elems / block of 256 threads) ----
__global__ void k_bsum(const int* __restrict__ deg, int N, int* __restrict__ bsum) {
    int base = blockIdx.x * 1024 + threadIdx.x * 4;
    int s = 0;
#pragma unroll
    for (int j = 0; j < 4; j++) { int i = base + j; if (i < N) s += deg[i]; }
    int lane = threadIdx.x & 63, wid = threadIdx.x >> 6;
#pragma unroll
    for (int m = 32; m >= 1; m >>= 1) s += __shfl_xor(s, m, 64);
    __shared__ int ws[4];
    if (lane == 0) ws[wid] = s;
    __syncthreads();
    if (threadIdx.x == 0) bsum[blockIdx.x] = ws[0] + ws[1] + ws[2] + ws[3];
}

__global__ void k_scan_bsums(const int* __restrict__ bsum, int* __restrict__ boff, int nb) {
    int t = threadIdx.x, lane = t & 63, wid = t >> 6;
    int v = (t < nb) ? bsum[t] : 0;
    int incl = wave_iscan(v, lane);
    __shared__ int ws[2];
    if (lane == 63) ws[wid] = incl;
    __syncthreads();
    int add = (wid == 1) ? ws[0] : 0;
    if (t < nb) boff[t] = add + incl - v;   // exclusive
}

__global__ void k_scan_final(const int* __restrict__ deg, int N, const int* __restrict__ boff,
                             int* __restrict__ row_ptr, int* __restrict__ cursor, int E) {
    int base = blockIdx.x * 1024 + threadIdx.x * 4;
    int v[4]; int tsum = 0;
#pragma unroll
    for (int j = 0; j < 4; j++) { int i = base + j; v[j] = (i < N) ? deg[i] : 0; tsum += v[j]; }
    int lane = threadIdx.x & 63, wid = threadIdx.x >> 6;
    int incl = wave_iscan(tsum, lane);
    __shared__ int ws[4];
    if (lane == 63) ws[wid] = incl;
    __syncthreads();
    if (threadIdx.x == 0) { int a = 0; for (int w = 0; w < 4; w++) { int t = ws[w]; ws[w] = a; a += t; } }
    __syncthreads();
    int off = boff[blockIdx.x] + ws[wid] + incl - tsum;   // exclusive offset of this thread's first elem
#pragma unroll
    for (int j = 0; j < 4; j++) {
        int i = base + j;
        if (i < N) { row_ptr[i] = off; cursor[i] = off; }
        off += v[j];
    }
    if (blockIdx.x == 0 && threadIdx.x == 0) row_ptr[N] = E;
}

// col[cursor[dst]++] = src
__global__ void k_fill(const int* __restrict__ src, const int* __restrict__ dst, int E,
                       int* __restrict__ cursor, int* __restrict__ col) {
    int e = blockIdx.x * blockDim.x + threadIdx.x;
    if (e < E) {
        int p = atomicAdd(&cursor[dst[e]], 1);
        col[p] = src[e];
    }
}

// dinv = rsqrt(deg+1); xs = x*dinv
__global__ void k_dinv(const int* __restrict__ deg, const float* __restrict__ x,
                       float* __restrict__ dinv, float* __restrict__ xs, int N) {
    int i = blockIdx.x * blockDim.x + threadIdx.x;
    if (i < N) {
        float d = rsqrtf((float)deg[i] + 1.0f);
        dinv[i] = d;
        xs[i] = x[i] * d;
    }
}

// Fused layer-1: 32 lanes/node. Cooperative gather of xs[col] (coalesced col reads),
// butterfly reduce, then per-channel dense: t2s[i][c] = dinv*( sum_j leaky(s1*W1[j]+b1[j]) * W2[j][c] )
__global__ void k_layer1f(const float* __restrict__ x, const float* __restrict__ dinv,
                          const float* __restrict__ xs, const int* __restrict__ row_ptr,
                          const int* __restrict__ col,
                          const float* __restrict__ W1, const float* __restrict__ b1,
                          const float* __restrict__ W2, float* __restrict__ t2s, int N) {
    __shared__ float sW1[64], sb1[64], sW2[64 * 32];
    for (int t = threadIdx.x; t < 64 * 32; t += blockDim.x) sW2[t] = W2[t];
    for (int t = threadIdx.x; t < 64; t += blockDim.x) { sW1[t] = W1[t]; sb1[t] = b1[t]; }
    __syncthreads();
    int tid = blockIdx.x * blockDim.x + threadIdx.x;
    int i = tid >> 5, c = tid & 31;
    bool valid = (i < N);
    int beg = valid ? row_ptr[i] : 0;
    int end = valid ? row_ptr[i + 1] : 0;
    float s = 0.f;
    for (int e = beg + c; e < end; e += 32) s += xs[col[e]];
#pragma unroll
    for (int m = 16; m >= 1; m >>= 1) s += __shfl_xor(s, m, 64);
    if (!valid) return;
    float di = dinv[i];
    float s1 = di * (s + xs[i]);
    float acc = 0.f;
#pragma unroll
    for (int j = 0; j < 64; j++) {
        float h = s1 * sW1[j] + sb1[j];
        h = LEAKY(h);
        acc += h * sW2[j * 32 + c];
    }
    t2s[(size_t)i * 32 + c] = di * acc;
}

// Fused layer-2: 32 lanes/node, lane = channel. Gather rows of t2s (128B coalesced per edge),
// h2 = leaky(dinv*(g + t2s[i][c]) + b2[c]); then t3s[i][k] = dinv * sum_c h2[c]*W3[c][k] via LDS.
__global__ void k_layer2f(const float* __restrict__ dinv, const int* __restrict__ row_ptr,
                          const int* __restrict__ col, const float* __restrict__ t2s,
                          const float* __restrict__ b2, const float* __restrict__ W3,
                          float* __restrict__ t3s, int N) {
    __shared__ float sb2[32], sW3[32 * 10];
    __shared__ float sh2[256];
    for (int t = threadIdx.x; t < 32 * 10; t += blockDim.x) sW3[t] = W3[t];
    for (int t = threadIdx.x; t < 32; t += blockDim.x) sb2[t] = b2[t];
    __syncthreads();
    int tid = blockIdx.x * blockDim.x + threadIdx.x;
    int i = tid >> 5, c = tid & 31;
    bool valid = (i < N);
    int beg = valid ? row_ptr[i] : 0;
    int end = valid ? row_ptr[i + 1] : 0;
    float g = 0.f;
    for (int e = beg; e < end; e++) {
        int sc = col[e];                    // broadcast (same line for all 32 lanes)
        g += t2s[(size_t)sc * 32 + c];      // 128B coalesced row read
    }
    float h2 = 0.f, di = 0.f;
    if (valid) {
        di = dinv[i];
        float v = di * (g + t2s[(size_t)i * 32 + c]) + sb2[c];
        h2 = LEAKY(v);
    }
    sh2[threadIdx.x] = h2;
    __syncthreads();
    if (valid && c < 10) {
        int base = (threadIdx.x >> 5) << 5;
        float a = 0.f;
#pragma unroll
        for (int cc = 0; cc < 32; cc++) a += sh2[base + cc] * sW3[cc * 10 + c];
        t3s[(size_t)i * 10 + c] = di * a;
    }
}

// Fused layer-3 + mean: 16 lanes/node (10 active). out[k] += dinv*(g + t3s[i][k]) + b3[k], scaled 1/N.
__global__ void k_agg3(const float* __restrict__ dinv, const int* __restrict__ row_ptr,
                       const int* __restrict__ col, const float* __restrict__ t3s,
                       const float* __restrict__ b3, float* __restrict__ out, int N, float invN) {
    __shared__ float sred[10];
    __shared__ float sb3[10];
    if (threadIdx.x < 10) { sred[threadIdx.x] = 0.f; sb3[threadIdx.x] = b3[threadIdx.x]; }
    __syncthreads();
    int tid = blockIdx.x * blockDim.x + threadIdx.x;
    int i = tid >> 4, k = tid & 15;
    if (i < N && k < 10) {
        int beg = row_ptr[i], end = row_ptr[i + 1];
        float g = 0.f;
        for (int e = beg; e < end; e++) g += t3s[(size_t)col[e] * 10 + k];
        float di = dinv[i];
        float v = di * (g + t3s[(size_t)i * 10 + k]) + sb3[k];
        atomicAdd(&sred[k], v * invN);
    }
    __syncthreads();
    if (threadIdx.x < 10) atomicAdd(&out[threadIdx.x], sred[threadIdx.x]);
}

extern "C" void kernel_launch(void* const* d_in, const int* in_sizes, int n_in,
                              void* d_out, int out_size, void* d_ws, size_t ws_size,
                              hipStream_t stream) {
    const float* x  = (const float*)d_in[0];
    const int*   ei = (const int*)d_in[1];
    const float* W1 = (const float*)d_in[2];
    const float* b1 = (const float*)d_in[3];
    const float* W2 = (const float*)d_in[4];
    const float* b2 = (const float*)d_in[5];
    const float* W3 = (const float*)d_in[6];
    const float* b3 = (const float*)d_in[7];
    float* out = (float*)d_out;

    const int N = in_sizes[0];
    const int E = in_sizes[1] / 2;
    const int* src = ei;
    const int* dst = ei + E;

    auto align256 = [](size_t v) { return (v + 255) & ~(size_t)255; };
    char* ws = (char*)d_ws;
    size_t off = 0;
    size_t o_deg  = off; off = align256(off + (size_t)N * 4);          // zeroed
    size_t zero_bytes = off;
    size_t o_rp   = off; off = align256(off + ((size_t)N + 1) * 4);
    size_t o_cur  = off; off = align256(off + (size_t)N * 4);
    size_t o_col  = off; off = align256(off + (size_t)E * 4);
    size_t o_dinv = off; off = align256(off + (size_t)N * 4);
    size_t o_xs   = off; off = align256(off + (size_t)N * 4);
    size_t o_t2s  = off; off = align256(off + (size_t)N * 32 * 4);
    size_t o_t3s  = off; off = align256(off + (size_t)N * 10 * 4);
    size_t o_bsum = off; off = align256(off + 1024 * 4);
    size_t o_boff = off; off = align256(off + 1024 * 4);

    int*   deg    = (int*)(ws + o_deg);
    int*   rp     = (int*)(ws + o_rp);
    int*   cur    = (int*)(ws + o_cur);
    int*   col    = (int*)(ws + o_col);
    float* dinv   = (float*)(ws + o_dinv);
    float* xs     = (float*)(ws + o_xs);
    float* t2s    = (float*)(ws + o_t2s);
    float* t3s    = (float*)(ws + o_t3s);
    int*   bsum   = (int*)(ws + o_bsum);
    int*   boff   = (int*)(ws + o_boff);

    const int B = 256;
    const int NB = (N + 1023) / 1024;  // scan blocks (<=128 required; N=100k -> 98)

    k_zero<<<128, B, 0, stream>>>((float4*)ws, zero_bytes / 16, out);
    k_deg<<<(E + B - 1) / B, B, 0, stream>>>(dst, E, deg);
    k_bsum<<<NB, B, 0, stream>>>(deg, N, bsum);
    k_scan_bsums<<<1, 128, 0, stream>>>(bsum, boff, NB);
    k_scan_final<<<NB, B, 0, stream>>>(deg, N, boff, rp, cur, E);
    k_fill<<<(E + B - 1) / B, B, 0, stream>>>(src, dst, E, cur, col);
    k_dinv<<<(N + B - 1) / B, B, 0, stream>>>(deg, x, dinv, xs, N);
    k_layer1f<<<((size_t)N * 32 + B - 1) / B, B, 0, stream>>>(x, dinv, xs, rp, col, W1, b1, W2, t2s, N);
    k_layer2f<<<((size_t)N * 32 + B - 1) / B, B, 0, stream>>>(dinv, rp, col, t2s, b2, W3, t3s, N);
    k_agg3<<<((size_t)N * 16 + B - 1) / B, B, 0, stream>>>(dinv, rp, col, t3s, b3, out, N, 1.0f / (float)N);
}

// Round 4
// 618.808 us; speedup vs baseline: 1.6581x; 1.3297x over previous
//
#include <hip/hip_runtime.h>

#define LEAKY(v) ((v) > 0.0f ? (v) : 0.1f * (v))

#define NPB 128          // nodes per bucket (power of 2)
#define NPB_SHIFT 7
#define CUR_STRIDE 16    // pad bucket counters to one per 64B line

__device__ __forceinline__ int wave_iscan(int v, int lane) {
#pragma unroll
    for (int off = 1; off < 64; off <<= 1) {
        int n = __shfl_up(v, off, 64);
        if (lane >= off) v += n;
    }
    return v;
}

// Zero the padded bucket-count region and out[10].
__global__ void k_zero(float4* p, size_t n4, float* out) {
    size_t i = (size_t)blockIdx.x * blockDim.x + threadIdx.x;
    size_t stride = (size_t)gridDim.x * blockDim.x;
    float4 z = {0.f, 0.f, 0.f, 0.f};
    for (; i < n4; i += stride) p[i] = z;
    if (blockIdx.x == 0 && threadIdx.x < 10) out[threadIdx.x] = 0.f;
}

// LDS-histogram dst into coarse buckets, flush once per workgroup.
__global__ void k_hist(const int* __restrict__ dst, int E, int* __restrict__ bcnt, int nbk) {
    __shared__ int h[1024];
    for (int t = threadIdx.x; t < nbk; t += blockDim.x) h[t] = 0;
    __syncthreads();
    for (int e = blockIdx.x * blockDim.x + threadIdx.x; e < E; e += gridDim.x * blockDim.x)
        atomicAdd(&h[dst[e] >> NPB_SHIFT], 1);
    __syncthreads();
    for (int t = threadIdx.x; t < nbk; t += blockDim.x)
        if (h[t]) atomicAdd(&bcnt[t * CUR_STRIDE], h[t]);
}

// Single-block exclusive scan of bucket counts (nbk <= 1024). block = 1024.
__global__ void k_scan_bkt(const int* __restrict__ bcnt, int* __restrict__ boff,
                           int* __restrict__ bcur, int nbk) {
    int t = threadIdx.x, lane = t & 63, wid = t >> 6;
    int v = (t < nbk) ? bcnt[t * CUR_STRIDE] : 0;
    int incl = wave_iscan(v, lane);
    __shared__ int wsum[16];
    if (lane == 63) wsum[wid] = incl;
    __syncthreads();
    if (t == 0) {
        int a = 0;
#pragma unroll
        for (int w = 0; w < 16; w++) { int s = wsum[w]; wsum[w] = a; a += s; }
        boff[nbk] = a;   // == E
    }
    __syncthreads();
    int ex = wsum[wid] + incl - v;
    if (t < nbk) { boff[t] = ex; bcur[t * CUR_STRIDE] = ex; }
}

// Scatter each edge into its bucket region as packed (src<<7)|local_dst.
// Only nbk advancing tails -> writes stay L2-resident.
__global__ void k_partition(const int* __restrict__ src, const int* __restrict__ dst, int E,
                            int* __restrict__ bcur, int* __restrict__ pk) {
    int e = blockIdx.x * blockDim.x + threadIdx.x;
    if (e < E) {
        int d = dst[e];
        int b = d >> NPB_SHIFT;
        int p = atomicAdd(&bcur[b * CUR_STRIDE], 1);
        pk[p] = (src[e] << NPB_SHIFT) | (d & (NPB - 1));
    }
}

// One workgroup per bucket: local deg histogram + scan -> row_ptr/dinv/xs,
// then LDS-cursor scatter of col into the bucket's contiguous region.
__global__ void k_build(const int* __restrict__ boff, const int* __restrict__ pk,
                        const float* __restrict__ x, int* __restrict__ row_ptr,
                        int* __restrict__ col, float* __restrict__ dinv,
                        float* __restrict__ xs, int N, int E) {
    __shared__ int cnt[NPB];
    __shared__ int cur[NPB];
    __shared__ int wsum2[4];
    int b = blockIdx.x;
    int node_base = b << NPB_SHIFT;
    int nodes = min(NPB, N - node_base);
    for (int t = threadIdx.x; t < NPB; t += blockDim.x) cnt[t] = 0;
    __syncthreads();
    int beg = boff[b], end = boff[b + 1];
    for (int e = beg + threadIdx.x; e < end; e += blockDim.x)
        atomicAdd(&cnt[pk[e] & (NPB - 1)], 1);
    __syncthreads();
    // exclusive scan of cnt[0..nodes) using first 2 waves (all threads execute; extra waves unused)
    int t = threadIdx.x, lane = t & 63, wid = t >> 6;
    int v = (t < nodes) ? cnt[t] : 0;
    int incl = wave_iscan(v, lane);
    if (lane == 63 && wid < 4) wsum2[wid] = incl;
    __syncthreads();
    int ex = incl - v + (wid == 1 ? wsum2[0] : 0);
    if (t < nodes) {
        int g = beg + ex;
        row_ptr[node_base + t] = g;
        cur[t] = g;
        float d = rsqrtf((float)cnt[t] + 1.0f);
        dinv[node_base + t] = d;
        xs[node_base + t] = x[node_base + t] * d;
    }
    if (b == 0 && t == 0) row_ptr[N] = E;
    __syncthreads();
    for (int e = beg + threadIdx.x; e < end; e += blockDim.x) {
        int pv = pk[e];
        int p = atomicAdd(&cur[pv & (NPB - 1)], 1);
        col[p] = ((unsigned)pv) >> NPB_SHIFT;
    }
}

// Fused layer-1: 32 lanes/node. Cooperative gather of xs[col], butterfly reduce,
// then per-channel dense: t2s[i][c] = dinv*( sum_j leaky(s1*W1[j]+b1[j]) * W2[j][c] )
__global__ void k_layer1f(const float* __restrict__ dinv, const float* __restrict__ xs,
                          const int* __restrict__ row_ptr, const int* __restrict__ col,
                          const float* __restrict__ W1, const float* __restrict__ b1,
                          const float* __restrict__ W2, float* __restrict__ t2s, int N) {
    __shared__ float sW1[64], sb1[64], sW2[64 * 32];
    for (int t = threadIdx.x; t < 64 * 32; t += blockDim.x) sW2[t] = W2[t];
    for (int t = threadIdx.x; t < 64; t += blockDim.x) { sW1[t] = W1[t]; sb1[t] = b1[t]; }
    __syncthreads();
    int tid = blockIdx.x * blockDim.x + threadIdx.x;
    int i = tid >> 5, c = tid & 31;
    bool valid = (i < N);
    int beg = valid ? row_ptr[i] : 0;
    int end = valid ? row_ptr[i + 1] : 0;
    float s = 0.f;
    for (int e = beg + c; e < end; e += 32) s += xs[col[e]];
#pragma unroll
    for (int m = 16; m >= 1; m >>= 1) s += __shfl_xor(s, m, 64);
    if (!valid) return;
    float di = dinv[i];
    float s1 = di * (s + xs[i]);
    float acc = 0.f;
#pragma unroll
    for (int j = 0; j < 64; j++) {
        float h = s1 * sW1[j] + sb1[j];
        h = LEAKY(h);
        acc += h * sW2[j * 32 + c];
    }
    t2s[(size_t)i * 32 + c] = di * acc;
}

// Fused layer-2: 32 lanes/node, lane = channel. Gather 128B rows of t2s per edge,
// h2 = leaky(dinv*(g + t2s[i][c]) + b2[c]); t3s[i][k] = dinv * sum_c h2[c]*W3[c][k].
__global__ void k_layer2f(const float* __restrict__ dinv, const int* __restrict__ row_ptr,
                          const int* __restrict__ col, const float* __restrict__ t2s,
                          const float* __restrict__ b2, const float* __restrict__ W3,
                          float* __restrict__ t3s, int N) {
    __shared__ float sb2[32], sW3[32 * 10];
    __shared__ float sh2[256];
    for (int t = threadIdx.x; t < 32 * 10; t += blockDim.x) sW3[t] = W3[t];
    for (int t = threadIdx.x; t < 32; t += blockDim.x) sb2[t] = b2[t];
    __syncthreads();
    int tid = blockIdx.x * blockDim.x + threadIdx.x;
    int i = tid >> 5, c = tid & 31;
    bool valid = (i < N);
    int beg = valid ? row_ptr[i] : 0;
    int end = valid ? row_ptr[i + 1] : 0;
    float g = 0.f;
    for (int e = beg; e < end; e++) {
        int sc = col[e];                    // wave-broadcast read
        g += t2s[(size_t)sc * 32 + c];      // 128B coalesced row read
    }
    float h2 = 0.f, di = 0.f;
    if (valid) {
        di = dinv[i];
        float v = di * (g + t2s[(size_t)i * 32 + c]) + sb2[c];
        h2 = LEAKY(v);
    }
    sh2[threadIdx.x] = h2;
    __syncthreads();
    if (valid && c < 10) {
        int base = (threadIdx.x >> 5) << 5;
        float a = 0.f;
#pragma unroll
        for (int cc = 0; cc < 32; cc++) a += sh2[base + cc] * sW3[cc * 10 + c];
        t3s[(size_t)i * 10 + c] = di * a;
    }
}

// Fused layer-3 + mean: 16 lanes/node (10 active).
__global__ void k_agg3(const float* __restrict__ dinv, const int* __restrict__ row_ptr,
                       const int* __restrict__ col, const float* __restrict__ t3s,
                       const float* __restrict__ b3, float* __restrict__ out, int N, float invN) {
    __shared__ float sred[10];
    __shared__ float sb3[10];
    if (threadIdx.x < 10) { sred[threadIdx.x] = 0.f; sb3[threadIdx.x] = b3[threadIdx.x]; }
    __syncthreads();
    int tid = blockIdx.x * blockDim.x + threadIdx.x;
    int i = tid >> 4, k = tid & 15;
    if (i < N && k < 10) {
        int beg = row_ptr[i], end = row_ptr[i + 1];
        float g = 0.f;
        for (int e = beg; e < end; e++) g += t3s[(size_t)col[e] * 10 + k];
        float di = dinv[i];
        float v = di * (g + t3s[(size_t)i * 10 + k]) + sb3[k];
        atomicAdd(&sred[k], v * invN);
    }
    __syncthreads();
    if (threadIdx.x < 10) atomicAdd(&out[threadIdx.x], sred[threadIdx.x]);
}

extern "C" void kernel_launch(void* const* d_in, const int* in_sizes, int n_in,
                              void* d_out, int out_size, void* d_ws, size_t ws_size,
                              hipStream_t stream) {
    const float* x  = (const float*)d_in[0];
    const int*   ei = (const int*)d_in[1];
    const float* W1 = (const float*)d_in[2];
    const float* b1 = (const float*)d_in[3];
    const float* W2 = (const float*)d_in[4];
    const float* b2 = (const float*)d_in[5];
    const float* W3 = (const float*)d_in[6];
    const float* b3 = (const float*)d_in[7];
    float* out = (float*)d_out;

    const int N = in_sizes[0];
    const int E = in_sizes[1] / 2;
    const int* src = ei;
    const int* dst = ei + E;
    const int NBK = (N + NPB - 1) >> NPB_SHIFT;   // 782 for N=100k (<=1024 required)

    auto align256 = [](size_t v) { return (v + 255) & ~(size_t)255; };
    char* ws = (char*)d_ws;
    size_t off = 0;
    size_t o_bcnt = off; off = align256(off + (size_t)NBK * CUR_STRIDE * 4);  // zeroed
    size_t zero_bytes = off;
    size_t o_bcur = off; off = align256(off + (size_t)NBK * CUR_STRIDE * 4);
    size_t o_boff = off; off = align256(off + ((size_t)NBK + 1) * 4);
    size_t o_pk   = off; off = align256(off + (size_t)E * 4);
    size_t o_rp   = off; off = align256(off + ((size_t)N + 1) * 4);
    size_t o_col  = off; off = align256(off + (size_t)E * 4);
    size_t o_dinv = off; off = align256(off + (size_t)N * 4);
    size_t o_xs   = off; off = align256(off + (size_t)N * 4);
    size_t o_t2s  = off; off = align256(off + (size_t)N * 32 * 4);
    size_t o_t3s  = off; off = align256(off + (size_t)N * 10 * 4);

    int*   bcnt = (int*)(ws + o_bcnt);
    int*   bcur = (int*)(ws + o_bcur);
    int*   boff = (int*)(ws + o_boff);
    int*   pk   = (int*)(ws + o_pk);
    int*   rp   = (int*)(ws + o_rp);
    int*   col  = (int*)(ws + o_col);
    float* dinv = (float*)(ws + o_dinv);
    float* xs   = (float*)(ws + o_xs);
    float* t2s  = (float*)(ws + o_t2s);
    float* t3s  = (float*)(ws + o_t3s);

    const int B = 256;
    k_zero<<<64, B, 0, stream>>>((float4*)ws, zero_bytes / 16, out);
    k_hist<<<256, B, 0, stream>>>(dst, E, bcnt, NBK);
    k_scan_bkt<<<1, 1024, 0, stream>>>(bcnt, boff, bcur, NBK);
    k_partition<<<(E + B - 1) / B, B, 0, stream>>>(src, dst, E, bcur, pk);
    k_build<<<NBK, B, 0, stream>>>(boff, pk, x, rp, col, dinv, xs, N, E);
    k_layer1f<<<((size_t)N * 32 + B - 1) / B, B, 0, stream>>>(dinv, xs, rp, col, W1, b1, W2, t2s, N);
    k_layer2f<<<((size_t)N * 32 + B - 1) / B, B, 0, stream>>>(dinv, rp, col, t2s, b2, W3, t3s, N);
    k_agg3<<<((size_t)N * 16 + B - 1) / B, B, 0, stream>>>(dinv, rp, col, t3s, b3, out, N, 1.0f / (float)N);
}

// Round 5
// 515.114 us; speedup vs baseline: 1.9919x; 1.2013x over previous
//
#include <hip/hip_runtime.h>

#define LEAKY(v) ((v) > 0.0f ? (v) : 0.1f * (v))

#define NPB 128          // nodes per bucket (power of 2)
#define NPB_SHIFT 7
#define CUR_STRIDE 16    // pad bucket counters to one per 64B line

typedef _Float16 f16;

__device__ __forceinline__ int wave_iscan(int v, int lane) {
#pragma unroll
    for (int off = 1; off < 64; off <<= 1) {
        int n = __shfl_up(v, off, 64);
        if (lane >= off) v += n;
    }
    return v;
}

// Zero the padded bucket-count region and out[10].
__global__ void k_zero(float4* p, size_t n4, float* out) {
    size_t i = (size_t)blockIdx.x * blockDim.x + threadIdx.x;
    size_t stride = (size_t)gridDim.x * blockDim.x;
    float4 z = {0.f, 0.f, 0.f, 0.f};
    for (; i < n4; i += stride) p[i] = z;
    if (blockIdx.x == 0 && threadIdx.x < 10) out[threadIdx.x] = 0.f;
}

// LDS-histogram dst into coarse buckets, flush once per workgroup.
__global__ void k_hist(const int* __restrict__ dst, int E, int* __restrict__ bcnt, int nbk) {
    __shared__ int h[1024];
    for (int t = threadIdx.x; t < nbk; t += blockDim.x) h[t] = 0;
    __syncthreads();
    for (int e = blockIdx.x * blockDim.x + threadIdx.x; e < E; e += gridDim.x * blockDim.x)
        atomicAdd(&h[dst[e] >> NPB_SHIFT], 1);
    __syncthreads();
    for (int t = threadIdx.x; t < nbk; t += blockDim.x)
        if (h[t]) atomicAdd(&bcnt[t * CUR_STRIDE], h[t]);
}

// Single-block exclusive scan of bucket counts (nbk <= 1024). block = 1024.
__global__ void k_scan_bkt(const int* __restrict__ bcnt, int* __restrict__ boff,
                           int* __restrict__ bcur, int nbk) {
    int t = threadIdx.x, lane = t & 63, wid = t >> 6;
    int v = (t < nbk) ? bcnt[t * CUR_STRIDE] : 0;
    int incl = wave_iscan(v, lane);
    __shared__ int wsum[16];
    if (lane == 63) wsum[wid] = incl;
    __syncthreads();
    if (t == 0) {
        int a = 0;
#pragma unroll
        for (int w = 0; w < 16; w++) { int s = wsum[w]; wsum[w] = a; a += s; }
        boff[nbk] = a;   // == E
    }
    __syncthreads();
    int ex = wsum[wid] + incl - v;
    if (t < nbk) { boff[t] = ex; bcur[t * CUR_STRIDE] = ex; }
}

// Scatter each edge into its bucket region as packed (src<<7)|local_dst.
__global__ void k_partition(const int* __restrict__ src, const int* __restrict__ dst, int E,
                            int* __restrict__ bcur, int* __restrict__ pk) {
    int e = blockIdx.x * blockDim.x + threadIdx.x;
    if (e < E) {
        int d = dst[e];
        int b = d >> NPB_SHIFT;
        int p = atomicAdd(&bcur[b * CUR_STRIDE], 1);
        pk[p] = (src[e] << NPB_SHIFT) | (d & (NPB - 1));
    }
}

// One workgroup per bucket: local deg histogram + scan -> row_ptr/dinv/xs,
// then LDS-cursor scatter of col into the bucket's contiguous region.
__global__ void k_build(const int* __restrict__ boff, const int* __restrict__ pk,
                        const float* __restrict__ x, int* __restrict__ row_ptr,
                        int* __restrict__ col, float* __restrict__ dinv,
                        float* __restrict__ xs, int N, int E) {
    __shared__ int cnt[NPB];
    __shared__ int cur[NPB];
    __shared__ int wsum2[4];
    int b = blockIdx.x;
    int node_base = b << NPB_SHIFT;
    int nodes = min(NPB, N - node_base);
    for (int t = threadIdx.x; t < NPB; t += blockDim.x) cnt[t] = 0;
    __syncthreads();
    int beg = boff[b], end = boff[b + 1];
    for (int e = beg + threadIdx.x; e < end; e += blockDim.x)
        atomicAdd(&cnt[pk[e] & (NPB - 1)], 1);
    __syncthreads();
    int t = threadIdx.x, lane = t & 63, wid = t >> 6;
    int v = (t < nodes) ? cnt[t] : 0;
    int incl = wave_iscan(v, lane);
    if (lane == 63 && wid < 4) wsum2[wid] = incl;
    __syncthreads();
    int ex = incl - v + (wid == 1 ? wsum2[0] : 0);
    if (t < nodes) {
        int g = beg + ex;
        row_ptr[node_base + t] = g;
        cur[t] = g;
        float d = rsqrtf((float)cnt[t] + 1.0f);
        dinv[node_base + t] = d;
        xs[node_base + t] = x[node_base + t] * d;
    }
    if (b == 0 && t == 0) row_ptr[N] = E;
    __syncthreads();
    for (int e = beg + threadIdx.x; e < end; e += blockDim.x) {
        int pv = pk[e];
        int p = atomicAdd(&cur[pv & (NPB - 1)], 1);
        col[p] = ((unsigned)pv) >> NPB_SHIFT;
    }
}

// Fused layer-1: 32 lanes/node. Cooperative gather of xs[col], butterfly reduce,
// then per-channel dense. t2s written as fp16.
__global__ void k_layer1f(const float* __restrict__ dinv, const float* __restrict__ xs,
                          const int* __restrict__ row_ptr, const int* __restrict__ col,
                          const float* __restrict__ W1, const float* __restrict__ b1,
                          const float* __restrict__ W2, f16* __restrict__ t2s, int N) {
    __shared__ float sW1[64], sb1[64], sW2[64 * 32];
    for (int t = threadIdx.x; t < 64 * 32; t += blockDim.x) sW2[t] = W2[t];
    for (int t = threadIdx.x; t < 64; t += blockDim.x) { sW1[t] = W1[t]; sb1[t] = b1[t]; }
    __syncthreads();
    int tid = blockIdx.x * blockDim.x + threadIdx.x;
    int i = tid >> 5, c = tid & 31;
    bool valid = (i < N);
    int beg = valid ? row_ptr[i] : 0;
    int end = valid ? row_ptr[i + 1] : 0;
    float s = 0.f;
    for (int e = beg + c; e < end; e += 32) s += xs[col[e]];
#pragma unroll
    for (int m = 16; m >= 1; m >>= 1) s += __shfl_xor(s, m, 64);
    if (!valid) return;
    float di = dinv[i];
    float s1 = di * (s + xs[i]);
    float acc = 0.f;
#pragma unroll
    for (int j = 0; j < 64; j++) {
        float h = s1 * sW1[j] + sb1[j];
        h = LEAKY(h);
        acc += h * sW2[j * 32 + c];
    }
    t2s[(size_t)i * 32 + c] = (f16)(di * acc);
}

// Fused layer-2: 32 lanes/node, lane = channel. Gather 64B fp16 rows, unroll x4 for MLP.
__global__ void k_layer2f(const float* __restrict__ dinv, const int* __restrict__ row_ptr,
                          const int* __restrict__ col, const f16* __restrict__ t2s,
                          const float* __restrict__ b2, const float* __restrict__ W3,
                          f16* __restrict__ t3s, int N) {
    __shared__ float sb2[32], sW3[32 * 10];
    __shared__ float sh2[256];
    for (int t = threadIdx.x; t < 32 * 10; t += blockDim.x) sW3[t] = W3[t];
    for (int t = threadIdx.x; t < 32; t += blockDim.x) sb2[t] = b2[t];
    __syncthreads();
    int tid = blockIdx.x * blockDim.x + threadIdx.x;
    int i = tid >> 5, c = tid & 31;
    bool valid = (i < N);
    int beg = valid ? row_ptr[i] : 0;
    int end = valid ? row_ptr[i + 1] : 0;
    float g0 = 0.f, g1 = 0.f, g2 = 0.f, g3 = 0.f;
    int e = beg;
    for (; e + 3 < end; e += 4) {
        int s0 = col[e], s1 = col[e + 1], s2 = col[e + 2], s3 = col[e + 3];
        g0 += (float)t2s[(size_t)s0 * 32 + c];
        g1 += (float)t2s[(size_t)s1 * 32 + c];
        g2 += (float)t2s[(size_t)s2 * 32 + c];
        g3 += (float)t2s[(size_t)s3 * 32 + c];
    }
    for (; e < end; e++) g0 += (float)t2s[(size_t)col[e] * 32 + c];
    float g = (g0 + g1) + (g2 + g3);
    float h2 = 0.f, di = 0.f;
    if (valid) {
        di = dinv[i];
        float v = di * (g + (float)t2s[(size_t)i * 32 + c]) + sb2[c];
        h2 = LEAKY(v);
    }
    sh2[threadIdx.x] = h2;
    __syncthreads();
    if (valid && c < 10) {
        int base = (threadIdx.x >> 5) << 5;
        float a = 0.f;
#pragma unroll
        for (int cc = 0; cc < 32; cc++) a += sh2[base + cc] * sW3[cc * 10 + c];
        t3s[(size_t)i * 10 + c] = (f16)(di * a);
    }
}

// Fused layer-3 + mean: 16 lanes/node (10 active), fp16 t3s, unroll x2.
__global__ void k_agg3(const float* __restrict__ dinv, const int* __restrict__ row_ptr,
                       const int* __restrict__ col, const f16* __restrict__ t3s,
                       const float* __restrict__ b3, float* __restrict__ out, int N, float invN) {
    __shared__ float sred[10];
    __shared__ float sb3[10];
    if (threadIdx.x < 10) { sred[threadIdx.x] = 0.f; sb3[threadIdx.x] = b3[threadIdx.x]; }
    __syncthreads();
    int tid = blockIdx.x * blockDim.x + threadIdx.x;
    int i = tid >> 4, k = tid & 15;
    if (i < N && k < 10) {
        int beg = row_ptr[i], end = row_ptr[i + 1];
        float g0 = 0.f, g1 = 0.f;
        int e = beg;
        for (; e + 1 < end; e += 2) {
            int s0 = col[e], s1 = col[e + 1];
            g0 += (float)t3s[(size_t)s0 * 10 + k];
            g1 += (float)t3s[(size_t)s1 * 10 + k];
        }
        if (e < end) g0 += (float)t3s[(size_t)col[e] * 10 + k];
        float di = dinv[i];
        float v = di * ((g0 + g1) + (float)t3s[(size_t)i * 10 + k]) + sb3[k];
        atomicAdd(&sred[k], v * invN);
    }
    __syncthreads();
    if (threadIdx.x < 10) atomicAdd(&out[threadIdx.x], sred[threadIdx.x]);
}

extern "C" void kernel_launch(void* const* d_in, const int* in_sizes, int n_in,
                              void* d_out, int out_size, void* d_ws, size_t ws_size,
                              hipStream_t stream) {
    const float* x  = (const float*)d_in[0];
    const int*   ei = (const int*)d_in[1];
    const float* W1 = (const float*)d_in[2];
    const float* b1 = (const float*)d_in[3];
    const float* W2 = (const float*)d_in[4];
    const float* b2 = (const float*)d_in[5];
    const float* W3 = (const float*)d_in[6];
    const float* b3 = (const float*)d_in[7];
    float* out = (float*)d_out;

    const int N = in_sizes[0];
    const int E = in_sizes[1] / 2;
    const int* src = ei;
    const int* dst = ei + E;
    const int NBK = (N + NPB - 1) >> NPB_SHIFT;

    auto align256 = [](size_t v) { return (v + 255) & ~(size_t)255; };
    char* ws = (char*)d_ws;
    size_t off = 0;
    size_t o_bcnt = off; off = align256(off + (size_t)NBK * CUR_STRIDE * 4);  // zeroed
    size_t zero_bytes = off;
    size_t o_bcur = off; off = align256(off + (size_t)NBK * CUR_STRIDE * 4);
    size_t o_boff = off; off = align256(off + ((size_t)NBK + 1) * 4);
    size_t o_pk   = off; off = align256(off + (size_t)E * 4);
    size_t o_rp   = off; off = align256(off + ((size_t)N + 1) * 4);
    size_t o_col  = off; off = align256(off + (size_t)E * 4);
    size_t o_dinv = off; off = align256(off + (size_t)N * 4);
    size_t o_xs   = off; off = align256(off + (size_t)N * 4);
    size_t o_t2s  = off; off = align256(off + (size_t)N * 32 * 2);
    size_t o_t3s  = off; off = align256(off + (size_t)N * 10 * 2);

    int*   bcnt = (int*)(ws + o_bcnt);
    int*   bcur = (int*)(ws + o_bcur);
    int*   boff = (int*)(ws + o_boff);
    int*   pk   = (int*)(ws + o_pk);
    int*   rp   = (int*)(ws + o_rp);
    int*   col  = (int*)(ws + o_col);
    float* dinv = (float*)(ws + o_dinv);
    float* xs   = (float*)(ws + o_xs);
    f16*   t2s  = (f16*)(ws + o_t2s);
    f16*   t3s  = (f16*)(ws + o_t3s);

    const int B = 256;
    k_zero<<<64, B, 0, stream>>>((float4*)ws, zero_bytes / 16, out);
    k_hist<<<256, B, 0, stream>>>(dst, E, bcnt, NBK);
    k_scan_bkt<<<1, 1024, 0, stream>>>(bcnt, boff, bcur, NBK);
    k_partition<<<(E + B - 1) / B, B, 0, stream>>>(src, dst, E, bcur, pk);
    k_build<<<NBK, B, 0, stream>>>(boff, pk, x, rp, col, dinv, xs, N, E);
    k_layer1f<<<((size_t)N * 32 + B - 1) / B, B, 0, stream>>>(dinv, xs, rp, col, W1, b1, W2, t2s, N);
    k_layer2f<<<((size_t)N * 32 + B - 1) / B, B, 0, stream>>>(dinv, rp, col, t2s, b2, W3, t3s, N);
    k_agg3<<<((size_t)N * 16 + B - 1) / B, B, 0, stream>>>(dinv, rp, col, t3s, b3, out, N, 1.0f / (float)N);
}

// Round 6
// 436.513 us; speedup vs baseline: 2.3506x; 1.1801x over previous
//
#include <hip/hip_runtime.h>

#define LEAKY(v) ((v) > 0.0f ? (v) : 0.1f * (v))

#define NPB 1024         // nodes per bucket (power of 2)
#define NPB_SHIFT 10
#define MAXBK 128        // max buckets (N <= 131072)
#define CUR_STRIDE 16    // pad bucket counters to one per 64B line
#define TILE 8192        // edges per partition block

typedef _Float16 f16;

__device__ __forceinline__ int wave_iscan(int v, int lane) {
#pragma unroll
    for (int off = 1; off < 64; off <<= 1) {
        int n = __shfl_up(v, off, 64);
        if (lane >= off) v += n;
    }
    return v;
}

// Zero the padded bucket-count region and out[10].
__global__ void k_zero(float4* p, size_t n4, float* out) {
    size_t i = (size_t)blockIdx.x * blockDim.x + threadIdx.x;
    size_t stride = (size_t)gridDim.x * blockDim.x;
    float4 z = {0.f, 0.f, 0.f, 0.f};
    for (; i < n4; i += stride) p[i] = z;
    if (blockIdx.x == 0 && threadIdx.x < 10) out[threadIdx.x] = 0.f;
}

// LDS-histogram dst into coarse buckets, flush once per workgroup.
__global__ void k_hist(const int* __restrict__ dst, int E, int* __restrict__ bcnt, int nbk) {
    __shared__ int h[MAXBK];
    for (int t = threadIdx.x; t < nbk; t += blockDim.x) h[t] = 0;
    __syncthreads();
    for (int e = blockIdx.x * blockDim.x + threadIdx.x; e < E; e += gridDim.x * blockDim.x)
        atomicAdd(&h[dst[e] >> NPB_SHIFT], 1);
    __syncthreads();
    for (int t = threadIdx.x; t < nbk; t += blockDim.x)
        if (h[t]) atomicAdd(&bcnt[t * CUR_STRIDE], h[t]);
}

// Single-block exclusive scan of bucket counts (nbk <= 128). block = 128.
__global__ void k_scan_bkt(const int* __restrict__ bcnt, int* __restrict__ boff,
                           int* __restrict__ bcur, int nbk) {
    int t = threadIdx.x, lane = t & 63, wid = t >> 6;
    int v = (t < nbk) ? bcnt[t * CUR_STRIDE] : 0;
    int incl = wave_iscan(v, lane);
    __shared__ int wsum[2];
    if (lane == 63) wsum[wid] = incl;
    __syncthreads();
    if (t == 0) boff[nbk] = wsum[0] + wsum[1];   // == E
    int ex = incl - v + (wid == 1 ? wsum[0] : 0);
    if (t < nbk) { boff[t] = ex; bcur[t * CUR_STRIDE] = ex; }
}

// Block-staged partition: LDS histogram over buckets, one global chunk
// reservation per (block,bucket), then scatter into block-owned chunks.
// Each 64B line of pk is written by (at most) one block except chunk edges.
__global__ void k_partition(const int* __restrict__ src, const int* __restrict__ dst, int E,
                            int* __restrict__ bcur, int* __restrict__ pk, int nbk) {
    __shared__ int hcnt[MAXBK], hcur[MAXBK], cbase[MAXBK];
    __shared__ int wsum[4];
    int tile_base = blockIdx.x * TILE;
    for (int t = threadIdx.x; t < nbk; t += blockDim.x) hcnt[t] = 0;
    __syncthreads();
    // phase A: local histogram
    for (int j = 0; j < TILE; j += blockDim.x) {
        int e = tile_base + j + threadIdx.x;
        if (e < E) atomicAdd(&hcnt[dst[e] >> NPB_SHIFT], 1);
    }
    __syncthreads();
    // phase B: scan (nbk <= 128 -> first 2 waves carry data) + chunk reserve
    int t = threadIdx.x, lane = t & 63, wid = t >> 6;
    int v = (t < nbk) ? hcnt[t] : 0;
    int incl = wave_iscan(v, lane);
    if (lane == 63) wsum[wid] = incl;
    __syncthreads();
    int ex = incl - v + (wid == 1 ? wsum[0] : 0);
    if (t < nbk) {
        hcur[t] = ex;
        int cb = (v > 0) ? atomicAdd(&bcur[t * CUR_STRIDE], v) : 0;
        cbase[t] = cb - ex;         // dest = cbase[b] + loc
    }
    __syncthreads();
    // phase C: scatter into block-owned chunks
    for (int j = 0; j < TILE; j += blockDim.x) {
        int e = tile_base + j + threadIdx.x;
        if (e < E) {
            int d = dst[e];
            int b = d >> NPB_SHIFT;
            int loc = atomicAdd(&hcur[b], 1);
            pk[cbase[b] + loc] = (src[e] << NPB_SHIFT) | (d & (NPB - 1));
        }
    }
}

// One workgroup (256 thr) per 1024-node bucket: LDS deg histogram + scan ->
// row_ptr/dinv/xs, then LDS-cursor scatter of col into the bucket's region.
__global__ void k_build(const int* __restrict__ boff, const int* __restrict__ pk,
                        const float* __restrict__ x, int* __restrict__ row_ptr,
                        int* __restrict__ col, float* __restrict__ dinv,
                        float* __restrict__ xs, int N, int E) {
    __shared__ int cnt[NPB];
    __shared__ int cur[NPB];
    __shared__ int wsum[4];
    int b = blockIdx.x;
    int node_base = b << NPB_SHIFT;
    for (int t = threadIdx.x; t < NPB; t += blockDim.x) cnt[t] = 0;
    __syncthreads();
    int beg = boff[b], end = boff[b + 1];
    for (int e = beg + threadIdx.x; e < end; e += blockDim.x)
        atomicAdd(&cnt[pk[e] & (NPB - 1)], 1);
    __syncthreads();
    // scan 1024 counts: 4 per thread
    int t = threadIdx.x, lane = t & 63, wid = t >> 6;
    int base4 = t * 4;
    int v0 = cnt[base4], v1 = cnt[base4 + 1], v2 = cnt[base4 + 2], v3 = cnt[base4 + 3];
    int tsum = v0 + v1 + v2 + v3;
    int incl = wave_iscan(tsum, lane);
    if (lane == 63) wsum[wid] = incl;
    __syncthreads();
    if (t == 0) { int a = 0; for (int w = 0; w < 4; w++) { int s = wsum[w]; wsum[w] = a; a += s; } }
    __syncthreads();
    int ex = wsum[wid] + incl - tsum;
    int offs[4] = { ex, ex + v0, ex + v0 + v1, ex + v0 + v1 + v2 };
    int vs[4] = { v0, v1, v2, v3 };
#pragma unroll
    for (int j = 0; j < 4; j++) {
        int ln = base4 + j;
        int i = node_base + ln;
        if (i < N) {
            int g = beg + offs[j];
            row_ptr[i] = g;
            cur[ln] = g;
            float d = rsqrtf((float)vs[j] + 1.0f);
            dinv[i] = d;
            xs[i] = x[i] * d;
        }
    }
    if (b == 0 && t == 0) row_ptr[N] = E;
    __syncthreads();
    for (int e = beg + threadIdx.x; e < end; e += blockDim.x) {
        int pv = pk[e];
        int p = atomicAdd(&cur[pv & (NPB - 1)], 1);
        col[p] = ((unsigned)pv) >> NPB_SHIFT;
    }
}

// Fused layer-1: 32 lanes/node. Cooperative gather of xs[col], butterfly reduce,
// then per-channel dense. t2s written as fp16.
__global__ void k_layer1f(const float* __restrict__ dinv, const float* __restrict__ xs,
                          const int* __restrict__ row_ptr, const int* __restrict__ col,
                          const float* __restrict__ W1, const float* __restrict__ b1,
                          const float* __restrict__ W2, f16* __restrict__ t2s, int N) {
    __shared__ float sW1[64], sb1[64], sW2[64 * 32];
    for (int t = threadIdx.x; t < 64 * 32; t += blockDim.x) sW2[t] = W2[t];
    for (int t = threadIdx.x; t < 64; t += blockDim.x) { sW1[t] = W1[t]; sb1[t] = b1[t]; }
    __syncthreads();
    int tid = blockIdx.x * blockDim.x + threadIdx.x;
    int i = tid >> 5, c = tid & 31;
    bool valid = (i < N);
    int beg = valid ? row_ptr[i] : 0;
    int end = valid ? row_ptr[i + 1] : 0;
    float s = 0.f;
    for (int e = beg + c; e < end; e += 32) s += xs[col[e]];
#pragma unroll
    for (int m = 16; m >= 1; m >>= 1) s += __shfl_xor(s, m, 64);
    if (!valid) return;
    float di = dinv[i];
    float s1 = di * (s + xs[i]);
    float acc = 0.f;
#pragma unroll
    for (int j = 0; j < 64; j++) {
        float h = s1 * sW1[j] + sb1[j];
        h = LEAKY(h);
        acc += h * sW2[j * 32 + c];
    }
    t2s[(size_t)i * 32 + c] = (f16)(di * acc);
}

// Fused layer-2: 32 lanes/node, lane = channel. Gather 64B fp16 rows, unroll x4.
__global__ void k_layer2f(const float* __restrict__ dinv, const int* __restrict__ row_ptr,
                          const int* __restrict__ col, const f16* __restrict__ t2s,
                          const float* __restrict__ b2, const float* __restrict__ W3,
                          f16* __restrict__ t3s, int N) {
    __shared__ float sb2[32], sW3[32 * 10];
    __shared__ float sh2[256];
    for (int t = threadIdx.x; t < 32 * 10; t += blockDim.x) sW3[t] = W3[t];
    for (int t = threadIdx.x; t < 32; t += blockDim.x) sb2[t] = b2[t];
    __syncthreads();
    int tid = blockIdx.x * blockDim.x + threadIdx.x;
    int i = tid >> 5, c = tid & 31;
    bool valid = (i < N);
    int beg = valid ? row_ptr[i] : 0;
    int end = valid ? row_ptr[i + 1] : 0;
    float g0 = 0.f, g1 = 0.f, g2 = 0.f, g3 = 0.f;
    int e = beg;
    for (; e + 3 < end; e += 4) {
        int s0 = col[e], s1 = col[e + 1], s2 = col[e + 2], s3 = col[e + 3];
        g0 += (float)t2s[(size_t)s0 * 32 + c];
        g1 += (float)t2s[(size_t)s1 * 32 + c];
        g2 += (float)t2s[(size_t)s2 * 32 + c];
        g3 += (float)t2s[(size_t)s3 * 32 + c];
    }
    for (; e < end; e++) g0 += (float)t2s[(size_t)col[e] * 32 + c];
    float g = (g0 + g1) + (g2 + g3);
    float h2 = 0.f, di = 0.f;
    if (valid) {
        di = dinv[i];
        float v = di * (g + (float)t2s[(size_t)i * 32 + c]) + sb2[c];
        h2 = LEAKY(v);
    }
    sh2[threadIdx.x] = h2;
    __syncthreads();
    if (valid && c < 10) {
        int base = (threadIdx.x >> 5) << 5;
        float a = 0.f;
#pragma unroll
        for (int cc = 0; cc < 32; cc++) a += sh2[base + cc] * sW3[cc * 10 + c];
        t3s[(size_t)i * 10 + c] = (f16)(di * a);
    }
}

// Fused layer-3 + mean: 16 lanes/node (10 active), fp16 t3s, unroll x2.
__global__ void k_agg3(const float* __restrict__ dinv, const int* __restrict__ row_ptr,
                       const int* __restrict__ col, const f16* __restrict__ t3s,
                       const float* __restrict__ b3, float* __restrict__ out, int N, float invN) {
    __shared__ float sred[10];
    __shared__ float sb3[10];
    if (threadIdx.x < 10) { sred[threadIdx.x] = 0.f; sb3[threadIdx.x] = b3[threadIdx.x]; }
    __syncthreads();
    int tid = blockIdx.x * blockDim.x + threadIdx.x;
    int i = tid >> 4, k = tid & 15;
    if (i < N && k < 10) {
        int beg = row_ptr[i], end = row_ptr[i + 1];
        float g0 = 0.f, g1 = 0.f;
        int e = beg;
        for (; e + 1 < end; e += 2) {
            int s0 = col[e], s1 = col[e + 1];
            g0 += (float)t3s[(size_t)s0 * 10 + k];
            g1 += (float)t3s[(size_t)s1 * 10 + k];
        }
        if (e < end) g0 += (float)t3s[(size_t)col[e] * 10 + k];
        float di = dinv[i];
        float v = di * ((g0 + g1) + (float)t3s[(size_t)i * 10 + k]) + sb3[k];
        atomicAdd(&sred[k], v * invN);
    }
    __syncthreads();
    if (threadIdx.x < 10) atomicAdd(&out[threadIdx.x], sred[threadIdx.x]);
}

extern "C" void kernel_launch(void* const* d_in, const int* in_sizes, int n_in,
                              void* d_out, int out_size, void* d_ws, size_t ws_size,
                              hipStream_t stream) {
    const float* x  = (const float*)d_in[0];
    const int*   ei = (const int*)d_in[1];
    const float* W1 = (const float*)d_in[2];
    const float* b1 = (const float*)d_in[3];
    const float* W2 = (const float*)d_in[4];
    const float* b2 = (const float*)d_in[5];
    const float* W3 = (const float*)d_in[6];
    const float* b3 = (const float*)d_in[7];
    float* out = (float*)d_out;

    const int N = in_sizes[0];
    const int E = in_sizes[1] / 2;
    const int* src = ei;
    const int* dst = ei + E;
    const int NBK = (N + NPB - 1) >> NPB_SHIFT;   // 98 for N=100k (must be <=128)

    auto align256 = [](size_t v) { return (v + 255) & ~(size_t)255; };
    char* ws = (char*)d_ws;
    size_t off = 0;
    size_t o_bcnt = off; off = align256(off + (size_t)NBK * CUR_STRIDE * 4);  // zeroed
    size_t zero_bytes = off;
    size_t o_bcur = off; off = align256(off + (size_t)NBK * CUR_STRIDE * 4);
    size_t o_boff = off; off = align256(off + ((size_t)NBK + 1) * 4);
    size_t o_pk   = off; off = align256(off + (size_t)E * 4);
    size_t o_rp   = off; off = align256(off + ((size_t)N + 1) * 4);
    size_t o_col  = off; off = align256(off + (size_t)E * 4);
    size_t o_dinv = off; off = align256(off + (size_t)N * 4);
    size_t o_xs   = off; off = align256(off + (size_t)N * 4);
    size_t o_t2s  = off; off = align256(off + (size_t)N * 32 * 2);
    size_t o_t3s  = off; off = align256(off + (size_t)N * 10 * 2);

    int*   bcnt = (int*)(ws + o_bcnt);
    int*   bcur = (int*)(ws + o_bcur);
    int*   boff = (int*)(ws + o_boff);
    int*   pk   = (int*)(ws + o_pk);
    int*   rp   = (int*)(ws + o_rp);
    int*   col  = (int*)(ws + o_col);
    float* dinv = (float*)(ws + o_dinv);
    float* xs   = (float*)(ws + o_xs);
    f16*   t2s  = (f16*)(ws + o_t2s);
    f16*   t3s  = (f16*)(ws + o_t3s);

    const int B = 256;
    k_zero<<<64, B, 0, stream>>>((float4*)ws, zero_bytes / 16, out);
    k_hist<<<256, B, 0, stream>>>(dst, E, bcnt, NBK);
    k_scan_bkt<<<1, 128, 0, stream>>>(bcnt, boff, bcur, NBK);
    k_partition<<<(E + TILE - 1) / TILE, B, 0, stream>>>(src, dst, E, bcur, pk, NBK);
    k_build<<<NBK, B, 0, stream>>>(boff, pk, x, rp, col, dinv, xs, N, E);
    k_layer1f<<<((size_t)N * 32 + B - 1) / B, B, 0, stream>>>(dinv, xs, rp, col, W1, b1, W2, t2s, N);
    k_layer2f<<<((size_t)N * 32 + B - 1) / B, B, 0, stream>>>(dinv, rp, col, t2s, b2, W3, t3s, N);
    k_agg3<<<((size_t)N * 16 + B - 1) / B, B, 0, stream>>>(dinv, rp, col, t3s, b3, out, N, 1.0f / (float)N);
}

// Round 7
// 379.646 us; speedup vs baseline: 2.7027x; 1.1498x over previous
//
#include <hip/hip_runtime.h>

#define LEAKY(v) ((v) > 0.0f ? (v) : 0.1f * (v))

#define NPB 1024         // nodes per bucket (power of 2)
#define NPB_SHIFT 10
#define MAXBK 128        // max buckets (N <= 131072)
#define CUR_STRIDE 16    // pad bucket counters to one per 64B line
#define TILE 8192        // edges per partition block

typedef _Float16 f16;

__device__ __forceinline__ int wave_iscan(int v, int lane) {
#pragma unroll
    for (int off = 1; off < 64; off <<= 1) {
        int n = __shfl_up(v, off, 64);
        if (lane >= off) v += n;
    }
    return v;
}

// Zero the padded bucket-count region; out[10] = b3 (agg3e accumulates onto it).
__global__ void k_zero(float4* p, size_t n4, float* out, const float* __restrict__ b3) {
    size_t i = (size_t)blockIdx.x * blockDim.x + threadIdx.x;
    size_t stride = (size_t)gridDim.x * blockDim.x;
    float4 z = {0.f, 0.f, 0.f, 0.f};
    for (; i < n4; i += stride) p[i] = z;
    if (blockIdx.x == 0 && threadIdx.x < 10) out[threadIdx.x] = b3[threadIdx.x];
}

// LDS-histogram dst into coarse buckets, flush once per workgroup.
__global__ void k_hist(const int* __restrict__ dst, int E, int* __restrict__ bcnt, int nbk) {
    __shared__ int h[MAXBK];
    for (int t = threadIdx.x; t < nbk; t += blockDim.x) h[t] = 0;
    __syncthreads();
    for (int e = blockIdx.x * blockDim.x + threadIdx.x; e < E; e += gridDim.x * blockDim.x)
        atomicAdd(&h[dst[e] >> NPB_SHIFT], 1);
    __syncthreads();
    for (int t = threadIdx.x; t < nbk; t += blockDim.x)
        if (h[t]) atomicAdd(&bcnt[t * CUR_STRIDE], h[t]);
}

// Single-block exclusive scan of bucket counts (nbk <= 128). block = 128.
__global__ void k_scan_bkt(const int* __restrict__ bcnt, int* __restrict__ boff,
                           int* __restrict__ bcur, int nbk) {
    int t = threadIdx.x, lane = t & 63, wid = t >> 6;
    int v = (t < nbk) ? bcnt[t * CUR_STRIDE] : 0;
    int incl = wave_iscan(v, lane);
    __shared__ int wsum[2];
    if (lane == 63) wsum[wid] = incl;
    __syncthreads();
    if (t == 0) boff[nbk] = wsum[0] + wsum[1];   // == E
    int ex = incl - v + (wid == 1 ? wsum[0] : 0);
    if (t < nbk) { boff[t] = ex; bcur[t * CUR_STRIDE] = ex; }
}

// Block-staged partition: LDS histogram over buckets, one global chunk
// reservation per (block,bucket), then scatter into block-owned chunks.
__global__ void k_partition(const int* __restrict__ src, const int* __restrict__ dst, int E,
                            int* __restrict__ bcur, int* __restrict__ pk, int nbk) {
    __shared__ int hcnt[MAXBK], hcur[MAXBK], cbase[MAXBK];
    __shared__ int wsum[4];
    int tile_base = blockIdx.x * TILE;
    for (int t = threadIdx.x; t < nbk; t += blockDim.x) hcnt[t] = 0;
    __syncthreads();
    for (int j = 0; j < TILE; j += blockDim.x) {
        int e = tile_base + j + threadIdx.x;
        if (e < E) atomicAdd(&hcnt[dst[e] >> NPB_SHIFT], 1);
    }
    __syncthreads();
    int t = threadIdx.x, lane = t & 63, wid = t >> 6;
    int v = (t < nbk) ? hcnt[t] : 0;
    int incl = wave_iscan(v, lane);
    if (lane == 63) wsum[wid] = incl;
    __syncthreads();
    int ex = incl - v + (wid == 1 ? wsum[0] : 0);
    if (t < nbk) {
        hcur[t] = ex;
        int cb = (v > 0) ? atomicAdd(&bcur[t * CUR_STRIDE], v) : 0;
        cbase[t] = cb - ex;         // dest = cbase[b] + loc
    }
    __syncthreads();
    for (int j = 0; j < TILE; j += blockDim.x) {
        int e = tile_base + j + threadIdx.x;
        if (e < E) {
            int d = dst[e];
            int b = d >> NPB_SHIFT;
            int loc = atomicAdd(&hcur[b], 1);
            pk[cbase[b] + loc] = (src[e] << NPB_SHIFT) | (d & (NPB - 1));
        }
    }
}

// One workgroup (256 thr) per 1024-node bucket: LDS deg histogram + scan ->
// row_ptr/dinv/xs, then LDS-cursor scatter of col into the bucket's region.
__global__ void k_build(const int* __restrict__ boff, const int* __restrict__ pk,
                        const float* __restrict__ x, int* __restrict__ row_ptr,
                        int* __restrict__ col, float* __restrict__ dinv,
                        float* __restrict__ xs, int N, int E) {
    __shared__ int cnt[NPB];
    __shared__ int cur[NPB];
    __shared__ int wsum[4];
    int b = blockIdx.x;
    int node_base = b << NPB_SHIFT;
    for (int t = threadIdx.x; t < NPB; t += blockDim.x) cnt[t] = 0;
    __syncthreads();
    int beg = boff[b], end = boff[b + 1];
    for (int e = beg + threadIdx.x; e < end; e += blockDim.x)
        atomicAdd(&cnt[pk[e] & (NPB - 1)], 1);
    __syncthreads();
    int t = threadIdx.x, lane = t & 63, wid = t >> 6;
    int base4 = t * 4;
    int v0 = cnt[base4], v1 = cnt[base4 + 1], v2 = cnt[base4 + 2], v3 = cnt[base4 + 3];
    int tsum = v0 + v1 + v2 + v3;
    int incl = wave_iscan(tsum, lane);
    if (lane == 63) wsum[wid] = incl;
    __syncthreads();
    if (t == 0) { int a = 0; for (int w = 0; w < 4; w++) { int s = wsum[w]; wsum[w] = a; a += s; } }
    __syncthreads();
    int ex = wsum[wid] + incl - tsum;
    int offs[4] = { ex, ex + v0, ex + v0 + v1, ex + v0 + v1 + v2 };
    int vs[4] = { v0, v1, v2, v3 };
#pragma unroll
    for (int j = 0; j < 4; j++) {
        int ln = base4 + j;
        int i = node_base + ln;
        if (i < N) {
            int g = beg + offs[j];
            row_ptr[i] = g;
            cur[ln] = g;
            float d = rsqrtf((float)vs[j] + 1.0f);
            dinv[i] = d;
            xs[i] = x[i] * d;
        }
    }
    if (b == 0 && t == 0) row_ptr[N] = E;
    __syncthreads();
    for (int e = beg + threadIdx.x; e < end; e += blockDim.x) {
        int pv = pk[e];
        int p = atomicAdd(&cur[pv & (NPB - 1)], 1);
        col[p] = ((unsigned)pv) >> NPB_SHIFT;
    }
}

// Fused layer-1: 32 lanes/node. Cooperative gather of xs[col], butterfly reduce,
// then per-channel dense. t2s written as fp16.
__global__ void k_layer1f(const float* __restrict__ dinv, const float* __restrict__ xs,
                          const int* __restrict__ row_ptr, const int* __restrict__ col,
                          const float* __restrict__ W1, const float* __restrict__ b1,
                          const float* __restrict__ W2, f16* __restrict__ t2s, int N) {
    __shared__ float sW1[64], sb1[64], sW2[64 * 32];
    for (int t = threadIdx.x; t < 64 * 32; t += blockDim.x) sW2[t] = W2[t];
    for (int t = threadIdx.x; t < 64; t += blockDim.x) { sW1[t] = W1[t]; sb1[t] = b1[t]; }
    __syncthreads();
    int tid = blockIdx.x * blockDim.x + threadIdx.x;
    int i = tid >> 5, c = tid & 31;
    bool valid = (i < N);
    int beg = valid ? row_ptr[i] : 0;
    int end = valid ? row_ptr[i + 1] : 0;
    float s = 0.f;
    for (int e = beg + c; e < end; e += 32) s += xs[col[e]];
#pragma unroll
    for (int m = 16; m >= 1; m >>= 1) s += __shfl_xor(s, m, 64);
    if (!valid) return;
    float di = dinv[i];
    float s1 = di * (s + xs[i]);
    float acc = 0.f;
#pragma unroll
    for (int j = 0; j < 64; j++) {
        float h = s1 * sW1[j] + sb1[j];
        h = LEAKY(h);
        acc += h * sW2[j * 32 + c];
    }
    t2s[(size_t)i * 32 + c] = (f16)(di * acc);
}

// Fused layer-2: 32 lanes/node, lane = channel. Gather 64B fp16 rows, unroll x4.
__global__ void k_layer2f(const float* __restrict__ dinv, const int* __restrict__ row_ptr,
                          const int* __restrict__ col, const f16* __restrict__ t2s,
                          const float* __restrict__ b2, const float* __restrict__ W3,
                          f16* __restrict__ t3s, int N) {
    __shared__ float sb2[32], sW3[32 * 10];
    __shared__ float sh2[256];
    for (int t = threadIdx.x; t < 32 * 10; t += blockDim.x) sW3[t] = W3[t];
    for (int t = threadIdx.x; t < 32; t += blockDim.x) sb2[t] = b2[t];
    __syncthreads();
    int tid = blockIdx.x * blockDim.x + threadIdx.x;
    int i = tid >> 5, c = tid & 31;
    bool valid = (i < N);
    int beg = valid ? row_ptr[i] : 0;
    int end = valid ? row_ptr[i + 1] : 0;
    float g0 = 0.f, g1 = 0.f, g2 = 0.f, g3 = 0.f;
    int e = beg;
    for (; e + 3 < end; e += 4) {
        int s0 = col[e], s1 = col[e + 1], s2 = col[e + 2], s3 = col[e + 3];
        g0 += (float)t2s[(size_t)s0 * 32 + c];
        g1 += (float)t2s[(size_t)s1 * 32 + c];
        g2 += (float)t2s[(size_t)s2 * 32 + c];
        g3 += (float)t2s[(size_t)s3 * 32 + c];
    }
    for (; e < end; e++) g0 += (float)t2s[(size_t)col[e] * 32 + c];
    float g = (g0 + g1) + (g2 + g3);
    float h2 = 0.f, di = 0.f;
    if (valid) {
        di = dinv[i];
        float v = di * (g + (float)t2s[(size_t)i * 32 + c]) + sb2[c];
        h2 = LEAKY(v);
    }
    sh2[threadIdx.x] = h2;
    __syncthreads();
    if (valid && c < 10) {
        int base = (threadIdx.x >> 5) << 5;
        float a = 0.f;
#pragma unroll
        for (int cc = 0; cc < 32; cc++) a += sh2[base + cc] * sW3[cc * 10 + c];
        t3s[(size_t)i * 10 + c] = (f16)(di * a);
    }
}

// Layer-3 + mean, edge-parallel (no CSR):
// out[k] = b3[k] + (1/N)·[ Σ_i dinv_i·t3s[i][k] + Σ_e dinv[dst_e]·t3s[src_e][k] ]
__global__ void k_agg3e(const int* __restrict__ src, const int* __restrict__ dst, int E,
                        const float* __restrict__ dinv, const f16* __restrict__ t3s, int N,
                        float* __restrict__ out, float invN) {
    float acc[10];
#pragma unroll
    for (int k = 0; k < 10; k++) acc[k] = 0.f;
    int stride = gridDim.x * blockDim.x;
    for (int e = blockIdx.x * blockDim.x + threadIdx.x; e < E; e += stride) {
        int s = src[e];
        float dd = dinv[dst[e]];
        const f16* row = t3s + (size_t)s * 10;
#pragma unroll
        for (int k = 0; k < 10; k++) acc[k] += dd * (float)row[k];
    }
    // self-loop terms: Σ_i dinv_i·t3s[i][k]
    for (int i = blockIdx.x * blockDim.x + threadIdx.x; i < N; i += stride) {
        float dd = dinv[i];
        const f16* row = t3s + (size_t)i * 10;
#pragma unroll
        for (int k = 0; k < 10; k++) acc[k] += dd * (float)row[k];
    }
    // wave butterfly reduce each channel
#pragma unroll
    for (int k = 0; k < 10; k++)
#pragma unroll
        for (int m = 32; m >= 1; m >>= 1) acc[k] += __shfl_xor(acc[k], m, 64);
    __shared__ float sred[10];
    if (threadIdx.x < 10) sred[threadIdx.x] = 0.f;
    __syncthreads();
    int lane = threadIdx.x & 63;
    if (lane < 10) atomicAdd(&sred[lane], acc[lane]);
    __syncthreads();
    if (threadIdx.x < 10) atomicAdd(&out[threadIdx.x], sred[threadIdx.x] * invN);
}

extern "C" void kernel_launch(void* const* d_in, const int* in_sizes, int n_in,
                              void* d_out, int out_size, void* d_ws, size_t ws_size,
                              hipStream_t stream) {
    const float* x  = (const float*)d_in[0];
    const int*   ei = (const int*)d_in[1];
    const float* W1 = (const float*)d_in[2];
    const float* b1 = (const float*)d_in[3];
    const float* W2 = (const float*)d_in[4];
    const float* b2 = (const float*)d_in[5];
    const float* W3 = (const float*)d_in[6];
    const float* b3 = (const float*)d_in[7];
    float* out = (float*)d_out;

    const int N = in_sizes[0];
    const int E = in_sizes[1] / 2;
    const int* src = ei;
    const int* dst = ei + E;
    const int NBK = (N + NPB - 1) >> NPB_SHIFT;   // 98 for N=100k (must be <=128)

    auto align256 = [](size_t v) { return (v + 255) & ~(size_t)255; };
    char* ws = (char*)d_ws;
    size_t off = 0;
    size_t o_bcnt = off; off = align256(off + (size_t)NBK * CUR_STRIDE * 4);  // zeroed
    size_t zero_bytes = off;
    size_t o_bcur = off; off = align256(off + (size_t)NBK * CUR_STRIDE * 4);
    size_t o_boff = off; off = align256(off + ((size_t)NBK + 1) * 4);
    size_t o_pk   = off; off = align256(off + (size_t)E * 4);
    size_t o_rp   = off; off = align256(off + ((size_t)N + 1) * 4);
    size_t o_col  = off; off = align256(off + (size_t)E * 4);
    size_t o_dinv = off; off = align256(off + (size_t)N * 4);
    size_t o_xs   = off; off = align256(off + (size_t)N * 4);
    size_t o_t2s  = off; off = align256(off + (size_t)N * 32 * 2);
    size_t o_t3s  = off; off = align256(off + (size_t)N * 10 * 2);

    int*   bcnt = (int*)(ws + o_bcnt);
    int*   bcur = (int*)(ws + o_bcur);
    int*   boff = (int*)(ws + o_boff);
    int*   pk   = (int*)(ws + o_pk);
    int*   rp   = (int*)(ws + o_rp);
    int*   col  = (int*)(ws + o_col);
    float* dinv = (float*)(ws + o_dinv);
    float* xs   = (float*)(ws + o_xs);
    f16*   t2s  = (f16*)(ws + o_t2s);
    f16*   t3s  = (f16*)(ws + o_t3s);

    const int B = 256;
    k_zero<<<64, B, 0, stream>>>((float4*)ws, zero_bytes / 16, out, b3);
    k_hist<<<256, B, 0, stream>>>(dst, E, bcnt, NBK);
    k_scan_bkt<<<1, 128, 0, stream>>>(bcnt, boff, bcur, NBK);
    k_partition<<<(E + TILE - 1) / TILE, B, 0, stream>>>(src, dst, E, bcur, pk, NBK);
    k_build<<<NBK, B, 0, stream>>>(boff, pk, x, rp, col, dinv, xs, N, E);
    k_layer1f<<<((size_t)N * 32 + B - 1) / B, B, 0, stream>>>(dinv, xs, rp, col, W1, b1, W2, t2s, N);
    k_layer2f<<<((size_t)N * 32 + B - 1) / B, B, 0, stream>>>(dinv, rp, col, t2s, b2, W3, t3s, N);
    k_agg3e<<<256, B, 0, stream>>>(src, dst, E, dinv, t3s, N, out, 1.0f / (float)N);
}

// Round 8
// 343.122 us; speedup vs baseline: 2.9904x; 1.1064x over previous
//
#include <hip/hip_runtime.h>

#define LEAKY(v) ((v) > 0.0f ? (v) : 0.1f * (v))

#define NPB 1024         // nodes per bucket (power of 2)
#define NPB_SHIFT 10
#define MAXBK 128        // max buckets (N <= 131072)
#define CUR_STRIDE 16    // pad bucket counters to one per 64B line
#define TILE 8192        // edges per partition block
#define SPLIT 8          // build blocks per bucket

typedef _Float16 f16;

__device__ __forceinline__ int wave_iscan(int v, int lane) {
#pragma unroll
    for (int off = 1; off < 64; off <<= 1) {
        int n = __shfl_up(v, off, 64);
        if (lane >= off) v += n;
    }
    return v;
}

// Zero bcnt+deg+acc1 region; out[10] = b3 (agg3e accumulates onto it).
__global__ void k_zero(float4* p, size_t n4, float* out, const float* __restrict__ b3) {
    size_t i = (size_t)blockIdx.x * blockDim.x + threadIdx.x;
    size_t stride = (size_t)gridDim.x * blockDim.x;
    float4 z = {0.f, 0.f, 0.f, 0.f};
    for (; i < n4; i += stride) p[i] = z;
    if (blockIdx.x == 0 && threadIdx.x < 10) out[threadIdx.x] = b3[threadIdx.x];
}

// LDS-histogram dst into coarse buckets, flush once per workgroup.
__global__ void k_hist(const int* __restrict__ dst, int E, int* __restrict__ bcnt, int nbk) {
    __shared__ int h[MAXBK];
    for (int t = threadIdx.x; t < nbk; t += blockDim.x) h[t] = 0;
    __syncthreads();
    for (int e = blockIdx.x * blockDim.x + threadIdx.x; e < E; e += gridDim.x * blockDim.x)
        atomicAdd(&h[dst[e] >> NPB_SHIFT], 1);
    __syncthreads();
    for (int t = threadIdx.x; t < nbk; t += blockDim.x)
        if (h[t]) atomicAdd(&bcnt[t * CUR_STRIDE], h[t]);
}

// Single-block exclusive scan of bucket counts (nbk <= 128). block = 128.
__global__ void k_scan_bkt(const int* __restrict__ bcnt, int* __restrict__ boff,
                           int* __restrict__ bcur, int nbk) {
    int t = threadIdx.x, lane = t & 63, wid = t >> 6;
    int v = (t < nbk) ? bcnt[t * CUR_STRIDE] : 0;
    int incl = wave_iscan(v, lane);
    __shared__ int wsum[2];
    if (lane == 63) wsum[wid] = incl;
    __syncthreads();
    if (t == 0) boff[nbk] = wsum[0] + wsum[1];   // == E
    int ex = incl - v + (wid == 1 ? wsum[0] : 0);
    if (t < nbk) { boff[t] = ex; bcur[t * CUR_STRIDE] = ex; }
}

// Block-staged partition: LDS histogram over buckets, one global chunk
// reservation per (block,bucket), then scatter into block-owned chunks.
__global__ void k_partition(const int* __restrict__ src, const int* __restrict__ dst, int E,
                            int* __restrict__ bcur, int* __restrict__ pk, int nbk) {
    __shared__ int hcnt[MAXBK], hcur[MAXBK], cbase[MAXBK];
    int tile_base = blockIdx.x * TILE;
    for (int t = threadIdx.x; t < nbk; t += blockDim.x) { hcnt[t] = 0; hcur[t] = 0; }
    __syncthreads();
    for (int j = 0; j < TILE; j += blockDim.x) {
        int e = tile_base + j + threadIdx.x;
        if (e < E) atomicAdd(&hcnt[dst[e] >> NPB_SHIFT], 1);
    }
    __syncthreads();
    for (int t = threadIdx.x; t < nbk; t += blockDim.x) {
        int v = hcnt[t];
        cbase[t] = (v > 0) ? atomicAdd(&bcur[t * CUR_STRIDE], v) : 0;
    }
    __syncthreads();
    for (int j = 0; j < TILE; j += blockDim.x) {
        int e = tile_base + j + threadIdx.x;
        if (e < E) {
            int d = dst[e];
            int b = d >> NPB_SHIFT;
            int loc = atomicAdd(&hcur[b], 1);
            pk[cbase[b] + loc] = (src[e] << NPB_SHIFT) | (d & (NPB - 1));
        }
    }
}

// Per-bucket-slice degree histogram -> global deg (contiguous atomic flush).
__global__ void k_deg2(const int* __restrict__ boff, const int* __restrict__ pk,
                       int* __restrict__ deg) {
    __shared__ int cnt[NPB];
    int b = blockIdx.y, s = blockIdx.x;
    int beg = boff[b], end = boff[b + 1], len = end - beg;
    int sb = beg + (int)(((long long)len * s) / SPLIT);
    int se = beg + (int)(((long long)len * (s + 1)) / SPLIT);
    for (int t = threadIdx.x; t < NPB; t += blockDim.x) cnt[t] = 0;
    __syncthreads();
    for (int e = sb + threadIdx.x; e < se; e += blockDim.x)
        atomicAdd(&cnt[pk[e] & (NPB - 1)], 1);
    __syncthreads();
    int node_base = b << NPB_SHIFT;
    for (int t = threadIdx.x; t < NPB; t += blockDim.x) {
        int c = cnt[t];
        if (c) atomicAdd(&deg[node_base + t], c);
    }
}

// One small block per bucket: scan 1024 deg -> row_ptr/gcur, dinv, xs.
__global__ void k_scan_nd(const int* __restrict__ boff, const int* __restrict__ deg,
                          const float* __restrict__ x, int* __restrict__ row_ptr,
                          int* __restrict__ gcur, float* __restrict__ dinv,
                          float* __restrict__ xs, int N, int E) {
    __shared__ int wsum[4];
    int b = blockIdx.x;
    int node_base = b << NPB_SHIFT;
    int beg = boff[b];
    int t = threadIdx.x, lane = t & 63, wid = t >> 6;
    int base4 = t * 4;
    int v[4]; int tsum = 0;
#pragma unroll
    for (int j = 0; j < 4; j++) {
        int i = node_base + base4 + j;
        v[j] = (i < N) ? deg[i] : 0;
        tsum += v[j];
    }
    int incl = wave_iscan(tsum, lane);
    if (lane == 63) wsum[wid] = incl;
    __syncthreads();
    if (t == 0) { int a = 0; for (int w = 0; w < 4; w++) { int s = wsum[w]; wsum[w] = a; a += s; } }
    __syncthreads();
    int ex = wsum[wid] + incl - tsum;
#pragma unroll
    for (int j = 0; j < 4; j++) {
        int i = node_base + base4 + j;
        if (i < N) {
            int g = beg + ex;
            row_ptr[i] = g;
            gcur[i] = g;
            float d = rsqrtf((float)v[j] + 1.0f);
            dinv[i] = d;
            xs[i] = x[i] * d;
        }
        ex += v[j];
    }
    if (b == 0 && t == 0) row_ptr[N] = E;
}

// Per-bucket-slice: chunk-reserve per node, scatter col via LDS cursors,
// and fuse layer-1 scalar aggregation: acc1[node] += sum xs[src].
__global__ void k_scat(const int* __restrict__ boff, const int* __restrict__ pk,
                       const float* __restrict__ xs, int* __restrict__ gcur,
                       int* __restrict__ col, float* __restrict__ acc1) {
    __shared__ int cnt[NPB];
    __shared__ int cbase[NPB];
    __shared__ float facc[NPB];
    int b = blockIdx.y, s = blockIdx.x;
    int beg = boff[b], end = boff[b + 1], len = end - beg;
    int sb = beg + (int)(((long long)len * s) / SPLIT);
    int se = beg + (int)(((long long)len * (s + 1)) / SPLIT);
    for (int t = threadIdx.x; t < NPB; t += blockDim.x) { cnt[t] = 0; facc[t] = 0.f; }
    __syncthreads();
    for (int e = sb + threadIdx.x; e < se; e += blockDim.x)
        atomicAdd(&cnt[pk[e] & (NPB - 1)], 1);
    __syncthreads();
    int node_base = b << NPB_SHIFT;
    for (int t = threadIdx.x; t < NPB; t += blockDim.x) {
        int c = cnt[t];
        cbase[t] = (c > 0) ? atomicAdd(&gcur[node_base + t], c) : 0;
        cnt[t] = 0;   // becomes local cursor
    }
    __syncthreads();
    for (int e = sb + threadIdx.x; e < se; e += blockDim.x) {
        int pv = pk[e];
        int ld = pv & (NPB - 1);
        int sn = (int)(((unsigned)pv) >> NPB_SHIFT);
        int loc = atomicAdd(&cnt[ld], 1);
        col[cbase[ld] + loc] = sn;
        atomicAdd(&facc[ld], xs[sn]);
    }
    __syncthreads();
    for (int t = threadIdx.x; t < NPB; t += blockDim.x) {
        float f = facc[t];
        if (f != 0.f) atomicAdd(&acc1[node_base + t], f);
    }
}

// Layer-1 dense only (aggregation already in acc1): 32 lanes/node.
// s1 = dinv*(acc1 + xs); t2s[i][c] = dinv * sum_j leaky(s1*W1[j]+b1[j])*W2[j][c]
__global__ void k_layer1d(const float* __restrict__ dinv, const float* __restrict__ xs,
                          const float* __restrict__ acc1,
                          const float* __restrict__ W1, const float* __restrict__ b1,
                          const float* __restrict__ W2, f16* __restrict__ t2s, int N) {
    __shared__ float sW1[64], sb1[64], sW2[64 * 32];
    for (int t = threadIdx.x; t < 64 * 32; t += blockDim.x) sW2[t] = W2[t];
    for (int t = threadIdx.x; t < 64; t += blockDim.x) { sW1[t] = W1[t]; sb1[t] = b1[t]; }
    __syncthreads();
    int tid = blockIdx.x * blockDim.x + threadIdx.x;
    int i = tid >> 5, c = tid & 31;
    if (i >= N) return;
    float di = dinv[i];
    float s1 = di * (acc1[i] + xs[i]);
    float acc = 0.f;
#pragma unroll
    for (int j = 0; j < 64; j++) {
        float h = s1 * sW1[j] + sb1[j];
        h = LEAKY(h);
        acc += h * sW2[j * 32 + c];
    }
    t2s[(size_t)i * 32 + c] = (f16)(di * acc);
}

// Fused layer-2: 32 lanes/node, lane = channel. Gather 64B fp16 rows, unroll x4.
__global__ void k_layer2f(const float* __restrict__ dinv, const int* __restrict__ row_ptr,
                          const int* __restrict__ col, const f16* __restrict__ t2s,
                          const float* __restrict__ b2, const float* __restrict__ W3,
                          f16* __restrict__ t3s, int N) {
    __shared__ float sb2[32], sW3[32 * 10];
    __shared__ float sh2[256];
    for (int t = threadIdx.x; t < 32 * 10; t += blockDim.x) sW3[t] = W3[t];
    for (int t = threadIdx.x; t < 32; t += blockDim.x) sb2[t] = b2[t];
    __syncthreads();
    int tid = blockIdx.x * blockDim.x + threadIdx.x;
    int i = tid >> 5, c = tid & 31;
    bool valid = (i < N);
    int beg = valid ? row_ptr[i] : 0;
    int end = valid ? row_ptr[i + 1] : 0;
    float g0 = 0.f, g1 = 0.f, g2 = 0.f, g3 = 0.f;
    int e = beg;
    for (; e + 3 < end; e += 4) {
        int s0 = col[e], s1 = col[e + 1], s2 = col[e + 2], s3 = col[e + 3];
        g0 += (float)t2s[(size_t)s0 * 32 + c];
        g1 += (float)t2s[(size_t)s1 * 32 + c];
        g2 += (float)t2s[(size_t)s2 * 32 + c];
        g3 += (float)t2s[(size_t)s3 * 32 + c];
    }
    for (; e < end; e++) g0 += (float)t2s[(size_t)col[e] * 32 + c];
    float g = (g0 + g1) + (g2 + g3);
    float h2 = 0.f, di = 0.f;
    if (valid) {
        di = dinv[i];
        float v = di * (g + (float)t2s[(size_t)i * 32 + c]) + sb2[c];
        h2 = LEAKY(v);
    }
    sh2[threadIdx.x] = h2;
    __syncthreads();
    if (valid && c < 10) {
        int base = (threadIdx.x >> 5) << 5;
        float a = 0.f;
#pragma unroll
        for (int cc = 0; cc < 32; cc++) a += sh2[base + cc] * sW3[cc * 10 + c];
        t3s[(size_t)i * 10 + c] = (f16)(di * a);
    }
}

// Layer-3 + mean, edge-parallel (no CSR).
__global__ void k_agg3e(const int* __restrict__ src, const int* __restrict__ dst, int E,
                        const float* __restrict__ dinv, const f16* __restrict__ t3s, int N,
                        float* __restrict__ out, float invN) {
    float acc[10];
#pragma unroll
    for (int k = 0; k < 10; k++) acc[k] = 0.f;
    int stride = gridDim.x * blockDim.x;
    for (int e = blockIdx.x * blockDim.x + threadIdx.x; e < E; e += stride) {
        int s = src[e];
        float dd = dinv[dst[e]];
        const f16* row = t3s + (size_t)s * 10;
#pragma unroll
        for (int k = 0; k < 10; k++) acc[k] += dd * (float)row[k];
    }
    for (int i = blockIdx.x * blockDim.x + threadIdx.x; i < N; i += stride) {
        float dd = dinv[i];
        const f16* row = t3s + (size_t)i * 10;
#pragma unroll
        for (int k = 0; k < 10; k++) acc[k] += dd * (float)row[k];
    }
#pragma unroll
    for (int k = 0; k < 10; k++)
#pragma unroll
        for (int m = 32; m >= 1; m >>= 1) acc[k] += __shfl_xor(acc[k], m, 64);
    __shared__ float sred[10];
    if (threadIdx.x < 10) sred[threadIdx.x] = 0.f;
    __syncthreads();
    int lane = threadIdx.x & 63;
    if (lane < 10) atomicAdd(&sred[lane], acc[lane]);
    __syncthreads();
    if (threadIdx.x < 10) atomicAdd(&out[threadIdx.x], sred[threadIdx.x] * invN);
}

extern "C" void kernel_launch(void* const* d_in, const int* in_sizes, int n_in,
                              void* d_out, int out_size, void* d_ws, size_t ws_size,
                              hipStream_t stream) {
    const float* x  = (const float*)d_in[0];
    const int*   ei = (const int*)d_in[1];
    const float* W1 = (const float*)d_in[2];
    const float* b1 = (const float*)d_in[3];
    const float* W2 = (const float*)d_in[4];
    const float* b2 = (const float*)d_in[5];
    const float* W3 = (const float*)d_in[6];
    const float* b3 = (const float*)d_in[7];
    float* out = (float*)d_out;

    const int N = in_sizes[0];
    const int E = in_sizes[1] / 2;
    const int* src = ei;
    const int* dst = ei + E;
    const int NBK = (N + NPB - 1) >> NPB_SHIFT;   // 98 for N=100k (must be <=128)

    auto align256 = [](size_t v) { return (v + 255) & ~(size_t)255; };
    char* ws = (char*)d_ws;
    size_t off = 0;
    // ---- zeroed region ----
    size_t o_bcnt = off; off = align256(off + (size_t)NBK * CUR_STRIDE * 4);
    size_t o_deg  = off; off = align256(off + (size_t)N * 4);
    size_t o_acc1 = off; off = align256(off + (size_t)N * 4);
    size_t zero_bytes = off;
    // ---- write-before-read region ----
    size_t o_bcur = off; off = align256(off + (size_t)NBK * CUR_STRIDE * 4);
    size_t o_boff = off; off = align256(off + ((size_t)NBK + 1) * 4);
    size_t o_pk   = off; off = align256(off + (size_t)E * 4);
    size_t o_rp   = off; off = align256(off + ((size_t)N + 1) * 4);
    size_t o_gcur = off; off = align256(off + (size_t)N * 4);
    size_t o_col  = off; off = align256(off + (size_t)E * 4);
    size_t o_dinv = off; off = align256(off + (size_t)N * 4);
    size_t o_xs   = off; off = align256(off + (size_t)N * 4);
    size_t o_t2s  = off; off = align256(off + (size_t)N * 32 * 2);
    size_t o_t3s  = off; off = align256(off + (size_t)N * 10 * 2);

    int*   bcnt = (int*)(ws + o_bcnt);
    int*   deg  = (int*)(ws + o_deg);
    float* acc1 = (float*)(ws + o_acc1);
    int*   bcur = (int*)(ws + o_bcur);
    int*   boff = (int*)(ws + o_boff);
    int*   pk   = (int*)(ws + o_pk);
    int*   rp   = (int*)(ws + o_rp);
    int*   gcur = (int*)(ws + o_gcur);
    int*   col  = (int*)(ws + o_col);
    float* dinv = (float*)(ws + o_dinv);
    float* xs   = (float*)(ws + o_xs);
    f16*   t2s  = (f16*)(ws + o_t2s);
    f16*   t3s  = (f16*)(ws + o_t3s);

    const int B = 256;
    k_zero<<<128, B, 0, stream>>>((float4*)ws, zero_bytes / 16, out, b3);
    k_hist<<<256, B, 0, stream>>>(dst, E, bcnt, NBK);
    k_scan_bkt<<<1, 128, 0, stream>>>(bcnt, boff, bcur, NBK);
    k_partition<<<(E + TILE - 1) / TILE, B, 0, stream>>>(src, dst, E, bcur, pk, NBK);
    k_deg2<<<dim3(SPLIT, NBK), B, 0, stream>>>(boff, pk, deg);
    k_scan_nd<<<NBK, B, 0, stream>>>(boff, deg, x, rp, gcur, dinv, xs, N, E);
    k_scat<<<dim3(SPLIT, NBK), B, 0, stream>>>(boff, pk, xs, gcur, col, acc1);
    k_layer1d<<<((size_t)N * 32 + B - 1) / B, B, 0, stream>>>(dinv, xs, acc1, W1, b1, W2, t2s, N);
    k_layer2f<<<((size_t)N * 32 + B - 1) / B, B, 0, stream>>>(dinv, rp, col, t2s, b2, W3, t3s, N);
    k_agg3e<<<256, B, 0, stream>>>(src, dst, E, dinv, t3s, N, out, 1.0f / (float)N);
}